// Round 4
// baseline (910.298 us; speedup 1.0000x reference)
//
#include <hip/hip_runtime.h>

// CoreSageLayer: x1 = (adj @ x)/deg ; out[k] = [x1|x] @ W[k] + bias, k=0..2
// N=8192, F=256, OUT=256. adj int32 in {0,1} (256 MB = the HBM floor).
//
// R4 vs R3 (phase1: 160us @ 954 GB/s, stall-bound: barrier-per-step drains
// the adj prefetch via vmcnt(0)-before-s_barrier every step):
//  - phase1 v4: ZERO barriers in the K-loop. A-frags built in-wave via
//    coalesced adj loads + ds_bpermute transpose (no LDS tile, no conflicts).
//    32x32x16 MFMA (m-tile 32/wave, full N=256) halves B-frag traffic.
//    Manual double-buffer of adj (depth 2) + B-frags; nothing ever drains.
//    Grid k-split x8 -> fp32 partials + partial deg in ws.
//  - reduce: sum 8 partials, /deg, pack bf16 into phase-2 A layout.
//  - prep & phase2 unchanged from R3 (phase2 ~10us, fine).

typedef unsigned short u16;
typedef int      i32x4 __attribute__((ext_vector_type(4)));
typedef unsigned u32x4 __attribute__((ext_vector_type(4)));
typedef float    f32x4 __attribute__((ext_vector_type(4)));
typedef float    f32x16 __attribute__((ext_vector_type(16)));

__device__ __forceinline__ u16 f2b(float f) {  // fp32 -> bf16 RNE
  unsigned u = __builtin_bit_cast(unsigned, f);
  return (u16)((u + 0x7FFFu + ((u >> 16) & 1u)) >> 16);
}
__device__ __forceinline__ unsigned pack2(float a, float b) {
  return (unsigned)f2b(a) | ((unsigned)f2b(b) << 16);
}
__device__ __forceinline__ f32x4 mfma16(u32x4 a, u32x4 b, f32x4 c) {
  // 16x16x32 bf16. A/B: lane holds row/col l&15, k=(l>>4)*8+j.
  // C/D: col=l&15, row=(l>>4)*4+reg.
  asm("v_mfma_f32_16x16x32_bf16 %0, %1, %2, %0" : "+v"(c) : "v"(a), "v"(b));
  return c;
}
__device__ __forceinline__ f32x16 mfma32(u32x4 a, u32x4 b, f32x16 c) {
  // 32x32x16 bf16. A: row=l&31, k=(l>>5)*8+j. B: col=l&31, k=(l>>5)*8+j.
  // C/D: col=l&31, row=(reg&3)+8*(reg>>2)+4*(l>>5).
  asm("v_mfma_f32_32x32x16_bf16 %0, %1, %2, %0" : "+v"(c) : "v"(a), "v"(b));
  return c;
}

// ---- prep (one dispatch):
// blocks [0,1024):    xtf  = x bf16, frag-major (k=node, n=feature). 4 MB.
// blocks [1024,2048): nxtf upper half = x bf16 frag-major (k=feat 256..511).
// blocks [2048,2240): wtf  = weight bf16 frag-major (k=feat, n=768 cols). 768 KB.
__global__ __launch_bounds__(256) void prep(const float* __restrict__ x,
                                            const float* __restrict__ wgt,
                                            u16* __restrict__ xtf,
                                            u16* __restrict__ nxtf,
                                            u16* __restrict__ wtf) {
  const int b = blockIdx.x, t = threadIdx.x;
  if (b < 1024) {
    int c = b * 256 + t, kc8 = c >> 8, f = c & 255;
    const float* p = x + (size_t)kc8 * 2048 + f;
    u32x4 h;
    h.x = pack2(p[0],    p[256]);  h.y = pack2(p[512],  p[768]);
    h.z = pack2(p[1024], p[1280]); h.w = pack2(p[1536], p[1792]);
    *(u32x4*)(xtf + (size_t)c * 8) = h;
  } else if (b < 2048) {
    int c = (b - 1024) * 256 + t, kc8r = c >> 13, m = c & 8191;
    const float* p = x + (size_t)m * 256 + kc8r * 8;
    f32x4 p0 = *(const f32x4*)p, p1 = *(const f32x4*)(p + 4);
    u32x4 h;
    h.x = pack2(p0.x, p0.y); h.y = pack2(p0.z, p0.w);
    h.z = pack2(p1.x, p1.y); h.w = pack2(p1.z, p1.w);
    *(u32x4*)(nxtf + ((size_t)(32 + kc8r) * 8192 + m) * 8) = h;
  } else {
    int idx = b - 2048, kc8 = idx / 3, c = (idx % 3) * 256 + t;
    int kk = c >> 8, o = c & 255;
    const float* p = wgt + (size_t)kk * 131072 + (size_t)kc8 * 2048 + o;
    u32x4 h;
    h.x = pack2(p[0],    p[256]);  h.y = pack2(p[512],  p[768]);
    h.z = pack2(p[1024], p[1280]); h.w = pack2(p[1536], p[1792]);
    *(u32x4*)(wtf + ((size_t)kc8 * 768 + c) * 8) = h;
  }
}

// ---- phase 1 v4: partial S = adj[m-tile, k-range] @ x, 32x32x16 MFMA.
// Grid (64 m-blocks, 8 k-splits) x 256 thr. Wave w: m-tile 32 rows
// (m0 = mb*128 + w*32), full N=256 (8 n-frags), K range kb*1024..+1024,
// 64 chunks of k=16. No __syncthreads anywhere in the loop.
__global__ __launch_bounds__(256, 2) void phase1(const int* __restrict__ adj,
                                                 const u16* __restrict__ xtf,
                                                 float* __restrict__ part,
                                                 int* __restrict__ degp) {
  const int t = threadIdx.x, l = t & 63, w = t >> 6;
  const int l31 = l & 31, l32 = l >> 5;
  const int m0 = blockIdx.x * 128 + w * 32;
  const int k0g = blockIdx.y * 1024;

  // adj source: lane loads row (l>>1), k-octet (l&1): 8 ints = 32 B, rows in
  // lane pairs -> 64 B contiguous per row per chunk, sequential over chunks.
  const int* abase = adj + (size_t)(m0 + (l >> 1)) * 8192 + k0g + (l & 1) * 8;
  // bpermute: target lane l pulls from source lane s holding (row=l31, oct=l32)
  const int bpidx = (((l31 << 1) | l32) << 2);
  // B frag base: k-octet chunk (k0g>>3) + step*2 + l32, col l31
  const u16* bbase = xtf + ((size_t)((k0g >> 3) + l32) * 256 + l31) * 8;

  f32x16 acc[8] = {};
  int dsum = 0;

  i32x4 pa[2][2];
  u32x4 bf[2][8];
  pa[0][0] = __builtin_nontemporal_load((const i32x4*)abase);
  pa[0][1] = __builtin_nontemporal_load((const i32x4*)abase + 1);
#pragma unroll
  for (int nt = 0; nt < 8; ++nt)
    bf[0][nt] = *(const u32x4*)(bbase + nt * 256);

#pragma unroll 2
  for (int step = 0; step < 64; ++step) {
    const int cur = step & 1, nxt = cur ^ 1;
    if (step < 63) {  // prefetch next chunk; nothing ever drains these
      pa[nxt][0] = __builtin_nontemporal_load((const i32x4*)(abase + (step + 1) * 16));
      pa[nxt][1] = __builtin_nontemporal_load((const i32x4*)(abase + (step + 1) * 16) + 1);
#pragma unroll
      for (int nt = 0; nt < 8; ++nt)
        bf[nxt][nt] = *(const u32x4*)(bbase + (step + 1) * 4096 + nt * 256);
    }
    i32x4 p0 = pa[cur][0], p1 = pa[cur][1];
    dsum += p0.x + p0.y + p0.z + p0.w + p1.x + p1.y + p1.z + p1.w;
    unsigned v0 = (p0.x ? 0x3F80u : 0u) | (p0.y ? 0x3F800000u : 0u);
    unsigned v1 = (p0.z ? 0x3F80u : 0u) | (p0.w ? 0x3F800000u : 0u);
    unsigned v2 = (p1.x ? 0x3F80u : 0u) | (p1.y ? 0x3F800000u : 0u);
    unsigned v3 = (p1.z ? 0x3F80u : 0u) | (p1.w ? 0x3F800000u : 0u);
    u32x4 a;   // in-wave transpose: no barrier, no bank conflicts
    a.x = (unsigned)__builtin_amdgcn_ds_bpermute(bpidx, (int)v0);
    a.y = (unsigned)__builtin_amdgcn_ds_bpermute(bpidx, (int)v1);
    a.z = (unsigned)__builtin_amdgcn_ds_bpermute(bpidx, (int)v2);
    a.w = (unsigned)__builtin_amdgcn_ds_bpermute(bpidx, (int)v3);
#pragma unroll
    for (int nt = 0; nt < 8; ++nt)
      acc[nt] = mfma32(a, bf[cur][nt], acc[nt]);
  }
  asm volatile("s_nop 7\n\ts_nop 7\n\ts_nop 7");  // MFMA D -> VALU read hazard

  // partial deg: row r held by lanes 2r (oct0) and 2r+1 (oct1)
  dsum += __shfl_xor(dsum, 1);
  if ((l & 1) == 0) degp[blockIdx.y * 8192 + m0 + (l >> 1)] = dsum;

  // partial C -> ws (fp32, plain row-major per k-split)
  float* pc = part + (size_t)blockIdx.y * 2097152 + (size_t)m0 * 256;
#pragma unroll
  for (int nt = 0; nt < 8; ++nt)
#pragma unroll
    for (int reg = 0; reg < 16; ++reg) {
      int row = (reg & 3) + 8 * (reg >> 2) + 4 * l32;
      pc[(size_t)row * 256 + nt * 32 + l31] = acc[nt][reg];
    }
}

// ---- reduce: x1 = (sum_kb part[kb]) / deg -> nxtf lower half (bf16 frag-major)
__global__ __launch_bounds__(256) void reducek(const float* __restrict__ part,
                                               const int* __restrict__ degp,
                                               u16* __restrict__ nxtf) {
  int c = blockIdx.x * 256 + threadIdx.x;   // 0..262143
  int m = c >> 5, kc8 = c & 31;
  int deg = 0;
#pragma unroll
  for (int kb = 0; kb < 8; ++kb) deg += degp[kb * 8192 + m];
  float rd = 1.0f / (float)deg;
  const float* p = part + (size_t)m * 256 + kc8 * 8;
  f32x4 s0 = {}, s1 = {};
#pragma unroll
  for (int kb = 0; kb < 8; ++kb) {
    s0 += *(const f32x4*)(p + (size_t)kb * 2097152);
    s1 += *(const f32x4*)(p + (size_t)kb * 2097152 + 4);
  }
  u32x4 h;
  h.x = pack2(s0.x * rd, s0.y * rd); h.y = pack2(s0.z * rd, s0.w * rd);
  h.z = pack2(s1.x * rd, s1.y * rd); h.w = pack2(s1.z * rd, s1.w * rd);
  *(u32x4*)(nxtf + ((size_t)kc8 * 8192 + m) * 8) = h;
}

// ---- phase 2: out[m, c=kk*256+o] = sum_k nx[m][k]*w_tf[c][k] + bias[o]
// M=8192 K=512 N=768. Zero LDS; both operands are ready frags in global.
__global__ __launch_bounds__(256) void phase2(const u16* __restrict__ nxtf,
                                              const u16* __restrict__ wtf,
                                              const float* __restrict__ bias,
                                              float* __restrict__ out) {
  const int t = threadIdx.x, l = t & 63, w = t >> 6;
  const int l15 = l & 15, l16 = l >> 4;
  const int m0 = blockIdx.x * 128, c0 = blockIdx.y * 48;
  f32x4 acc[2][3] = {};
  const u16* abase = nxtf + (size_t)l16 * 65536 + (size_t)(m0 + w * 32 + l15) * 8;
  const u16* bbase = wtf  + (size_t)l16 * 6144  + (size_t)(c0 + l15) * 8;
  float bv[3];
#pragma unroll
  for (int nt = 0; nt < 3; ++nt) bv[nt] = bias[(c0 + nt * 16 + l15) & 255];
#pragma unroll 2
  for (int step = 0; step < 16; ++step) {        // K: 32 per step
    u32x4 a[2], b[3];
    a[0] = *(const u32x4*)(abase + (size_t)step * 262144);
    a[1] = *(const u32x4*)(abase + (size_t)step * 262144 + 128);
#pragma unroll
    for (int nt = 0; nt < 3; ++nt)
      b[nt] = *(const u32x4*)(bbase + (size_t)step * 24576 + nt * 128);
#pragma unroll
    for (int mt2 = 0; mt2 < 2; ++mt2)
#pragma unroll
      for (int nt = 0; nt < 3; ++nt)
        acc[mt2][nt] = mfma16(a[mt2], b[nt], acc[mt2][nt]);
  }
  asm volatile("s_nop 7\n\ts_nop 7\n\ts_nop 7");
#pragma unroll
  for (int mt2 = 0; mt2 < 2; ++mt2)
#pragma unroll
    for (int nt = 0; nt < 3; ++nt) {
      int c = c0 + nt * 16 + l15;
      int kk = c >> 8, o = c & 255;
      float* op = out + (size_t)kk * 2097152 +
                  (size_t)(m0 + w * 32 + mt2 * 16 + l16 * 4) * 256 + o;
#pragma unroll
      for (int i = 0; i < 4; ++i)
        __builtin_nontemporal_store(acc[mt2][nt][i] + bv[nt], op + (size_t)i * 256);
    }
}

extern "C" void kernel_launch(void* const* d_in, const int* in_sizes, int n_in,
                              void* d_out, int out_size, void* d_ws, size_t ws_size,
                              hipStream_t stream) {
  (void)in_sizes; (void)n_in; (void)out_size; (void)ws_size;
  const float* x    = (const float*)d_in[1];
  const int*   adj  = (const int*)d_in[2];
  const float* wgt  = (const float*)d_in[3];
  const float* bias = (const float*)d_in[4];
  float* out = (float*)d_out;

  char* ws = (char*)d_ws;
  u16*   xtf  = (u16*)ws;                       // 4 MB
  u16*   nxtf = (u16*)(ws + (4ull  << 20));     // 8 MB
  u16*   wtf  = (u16*)(ws + (12ull << 20));     // 768 KB (pad to 1 MB)
  float* part = (float*)(ws + (13ull << 20));   // 64 MB (8 x 8192 x 256 f32)
  int*   degp = (int*)(ws + (77ull << 20));     // 256 KB

  prep   <<<2240, 256, 0, stream>>>(x, wgt, xtf, nxtf, wtf);
  phase1 <<<dim3(64, 8), 256, 0, stream>>>(adj, xtf, part, degp);
  reducek<<<1024, 256, 0, stream>>>(part, degp, nxtf);
  phase2 <<<dim3(64, 16), 256, 0, stream>>>(nxtf, wtf, bias, out);
}

// Round 5
// 859.563 us; speedup vs baseline: 1.0590x; 1.0590x over previous
//
#include <hip/hip_runtime.h>

// CoreSageLayer: x1 = (adj @ x)/deg ; out[k] = [x1|x] @ W[k] + bias, k=0..2
// N=8192, F=256, OUT=256. adj int32 in {0,1} (256 MB = the HBM floor).
//
// R5 vs R4 (phase1 595us: VGPR_Count=84 -> the f32x16 acc[8] (128 regs of
// contiguous 16-tuples, "+v" constraint) was SPILLED to scratch: WRITE 1.1GB,
// FETCH 636MB, MfmaUtil 2.3%):
//  - mfma32 accumulators moved to AGPRs via "+a" asm constraint. 128 AGPRs
//    (clean 16-aligned tuples in the empty accumulator half of the unified
//    file) + ~110 VGPRs for bf/pa/addressing fits the 256/wave budget at
//    2 blocks/CU. No other structural change (isolates the spill theory).

typedef unsigned short u16;
typedef int      i32x4 __attribute__((ext_vector_type(4)));
typedef unsigned u32x4 __attribute__((ext_vector_type(4)));
typedef float    f32x4 __attribute__((ext_vector_type(4)));
typedef float    f32x16 __attribute__((ext_vector_type(16)));

__device__ __forceinline__ u16 f2b(float f) {  // fp32 -> bf16 RNE
  unsigned u = __builtin_bit_cast(unsigned, f);
  return (u16)((u + 0x7FFFu + ((u >> 16) & 1u)) >> 16);
}
__device__ __forceinline__ unsigned pack2(float a, float b) {
  return (unsigned)f2b(a) | ((unsigned)f2b(b) << 16);
}
__device__ __forceinline__ f32x4 mfma16(u32x4 a, u32x4 b, f32x4 c) {
  // 16x16x32 bf16. A/B: lane holds row/col l&15, k=(l>>4)*8+j.
  // C/D: col=l&15, row=(l>>4)*4+reg.
  asm("v_mfma_f32_16x16x32_bf16 %0, %1, %2, %0" : "+v"(c) : "v"(a), "v"(b));
  return c;
}

// ---- prep (one dispatch):
// blocks [0,1024):    xtf  = x bf16, frag-major (k=node, n=feature). 4 MB.
// blocks [1024,2048): nxtf upper half = x bf16 frag-major (k=feat 256..511).
// blocks [2048,2240): wtf  = weight bf16 frag-major (k=feat, n=768 cols). 768 KB.
__global__ __launch_bounds__(256) void prep(const float* __restrict__ x,
                                            const float* __restrict__ wgt,
                                            u16* __restrict__ xtf,
                                            u16* __restrict__ nxtf,
                                            u16* __restrict__ wtf) {
  const int b = blockIdx.x, t = threadIdx.x;
  if (b < 1024) {
    int c = b * 256 + t, kc8 = c >> 8, f = c & 255;
    const float* p = x + (size_t)kc8 * 2048 + f;
    u32x4 h;
    h.x = pack2(p[0],    p[256]);  h.y = pack2(p[512],  p[768]);
    h.z = pack2(p[1024], p[1280]); h.w = pack2(p[1536], p[1792]);
    *(u32x4*)(xtf + (size_t)c * 8) = h;
  } else if (b < 2048) {
    int c = (b - 1024) * 256 + t, kc8r = c >> 13, m = c & 8191;
    const float* p = x + (size_t)m * 256 + kc8r * 8;
    f32x4 p0 = *(const f32x4*)p, p1 = *(const f32x4*)(p + 4);
    u32x4 h;
    h.x = pack2(p0.x, p0.y); h.y = pack2(p0.z, p0.w);
    h.z = pack2(p1.x, p1.y); h.w = pack2(p1.z, p1.w);
    *(u32x4*)(nxtf + ((size_t)(32 + kc8r) * 8192 + m) * 8) = h;
  } else {
    int idx = b - 2048, kc8 = idx / 3, c = (idx % 3) * 256 + t;
    int kk = c >> 8, o = c & 255;
    const float* p = wgt + (size_t)kk * 131072 + (size_t)kc8 * 2048 + o;
    u32x4 h;
    h.x = pack2(p[0],    p[256]);  h.y = pack2(p[512],  p[768]);
    h.z = pack2(p[1024], p[1280]); h.w = pack2(p[1536], p[1792]);
    *(u32x4*)(wtf + ((size_t)kc8 * 768 + c) * 8) = h;
  }
}

// ---- phase 1 v5: partial S = adj[m-tile, k-range] @ x, 32x32x16 MFMA,
// accumulators in AGPRs. Grid (64 m-blocks, 8 k-splits) x 256 thr.
// Wave w: m-tile 32 rows (m0 = mb*128 + w*32), full N=256 (8 n-frags),
// K range kb*1024..+1024, 64 chunks of k=16. No barriers in the loop.
__global__ __launch_bounds__(256, 2) void phase1(const int* __restrict__ adj,
                                                 const u16* __restrict__ xtf,
                                                 float* __restrict__ part,
                                                 int* __restrict__ degp) {
  const int t = threadIdx.x, l = t & 63, w = t >> 6;
  const int l31 = l & 31, l32 = l >> 5;
  const int m0 = blockIdx.x * 128 + w * 32;
  const int k0g = blockIdx.y * 1024;

  // adj source: lane loads row (l>>1), k-octet (l&1): 8 ints = 32 B.
  const int* abase = adj + (size_t)(m0 + (l >> 1)) * 8192 + k0g + (l & 1) * 8;
  // bpermute: target lane l pulls from source lane s = (l31<<1)|l32
  const int bpidx = (((l31 << 1) | l32) << 2);
  // B frag base: k-octet chunk (k0g>>3) + step*2 + l32, col l31
  const u16* bbase = xtf + ((size_t)((k0g >> 3) + l32) * 256 + l31) * 8;

  f32x16 acc[8] = {};   // lives in AGPRs (see "+a" below)
  int dsum = 0;

  i32x4 pa[2][2];
  u32x4 bf[2][8];
  pa[0][0] = __builtin_nontemporal_load((const i32x4*)abase);
  pa[0][1] = __builtin_nontemporal_load((const i32x4*)abase + 1);
#pragma unroll
  for (int nt = 0; nt < 8; ++nt)
    bf[0][nt] = *(const u32x4*)(bbase + nt * 256);

#pragma unroll 2
  for (int step = 0; step < 64; ++step) {
    const int cur = step & 1, nxt = cur ^ 1;
    if (step < 63) {  // prefetch next chunk; nothing ever drains these
      pa[nxt][0] = __builtin_nontemporal_load((const i32x4*)(abase + (step + 1) * 16));
      pa[nxt][1] = __builtin_nontemporal_load((const i32x4*)(abase + (step + 1) * 16) + 1);
#pragma unroll
      for (int nt = 0; nt < 8; ++nt)
        bf[nxt][nt] = *(const u32x4*)(bbase + (step + 1) * 4096 + nt * 256);
    }
    i32x4 p0 = pa[cur][0], p1 = pa[cur][1];
    dsum += p0.x + p0.y + p0.z + p0.w + p1.x + p1.y + p1.z + p1.w;
    unsigned v0 = (p0.x ? 0x3F80u : 0u) | (p0.y ? 0x3F800000u : 0u);
    unsigned v1 = (p0.z ? 0x3F80u : 0u) | (p0.w ? 0x3F800000u : 0u);
    unsigned v2 = (p1.x ? 0x3F80u : 0u) | (p1.y ? 0x3F800000u : 0u);
    unsigned v3 = (p1.z ? 0x3F80u : 0u) | (p1.w ? 0x3F800000u : 0u);
    u32x4 a;   // in-wave transpose: no barrier, no LDS tile
    a.x = (unsigned)__builtin_amdgcn_ds_bpermute(bpidx, (int)v0);
    a.y = (unsigned)__builtin_amdgcn_ds_bpermute(bpidx, (int)v1);
    a.z = (unsigned)__builtin_amdgcn_ds_bpermute(bpidx, (int)v2);
    a.w = (unsigned)__builtin_amdgcn_ds_bpermute(bpidx, (int)v3);
#pragma unroll
    for (int nt = 0; nt < 8; ++nt)
      // 32x32x16 bf16, acc pinned to AGPRs: "+a" gives the allocator a clean
      // 16-aligned tuple in the accumulator half of the unified file (the
      // "+v" version spilled: VGPR_Count=84, 1GB scratch traffic in R4).
      asm("v_mfma_f32_32x32x16_bf16 %0, %1, %2, %0"
          : "+a"(acc[nt]) : "v"(a), "v"(bf[cur][nt]));
  }
  asm volatile("s_nop 7\n\ts_nop 7\n\ts_nop 7");  // MFMA D -> read hazard

  // partial deg: row r held by lanes 2r (oct0) and 2r+1 (oct1)
  dsum += __shfl_xor(dsum, 1);
  if ((l & 1) == 0) degp[blockIdx.y * 8192 + m0 + (l >> 1)] = dsum;

  // partial C -> ws (fp32, row-major per k-split). C/D: col=l31,
  // row=(reg&3)+8*(reg>>2)+4*l32.
  float* pc = part + (size_t)blockIdx.y * 2097152 + (size_t)m0 * 256;
#pragma unroll
  for (int nt = 0; nt < 8; ++nt)
#pragma unroll
    for (int reg = 0; reg < 16; ++reg) {
      int row = (reg & 3) + 8 * (reg >> 2) + 4 * l32;
      pc[(size_t)row * 256 + nt * 32 + l31] = acc[nt][reg];
    }
}

// ---- reduce: x1 = (sum_kb part[kb]) / deg -> nxtf lower half (bf16 frag-major)
__global__ __launch_bounds__(256) void reducek(const float* __restrict__ part,
                                               const int* __restrict__ degp,
                                               u16* __restrict__ nxtf) {
  int c = blockIdx.x * 256 + threadIdx.x;   // 0..262143
  int m = c >> 5, kc8 = c & 31;
  int deg = 0;
#pragma unroll
  for (int kb = 0; kb < 8; ++kb) deg += degp[kb * 8192 + m];
  float rd = 1.0f / (float)deg;
  const float* p = part + (size_t)m * 256 + kc8 * 8;
  f32x4 s0 = {}, s1 = {};
#pragma unroll
  for (int kb = 0; kb < 8; ++kb) {
    s0 += *(const f32x4*)(p + (size_t)kb * 2097152);
    s1 += *(const f32x4*)(p + (size_t)kb * 2097152 + 4);
  }
  u32x4 h;
  h.x = pack2(s0.x * rd, s0.y * rd); h.y = pack2(s0.z * rd, s0.w * rd);
  h.z = pack2(s1.x * rd, s1.y * rd); h.w = pack2(s1.z * rd, s1.w * rd);
  *(u32x4*)(nxtf + ((size_t)kc8 * 8192 + m) * 8) = h;
}

// ---- phase 2: out[m, c=kk*256+o] = sum_k nx[m][k]*w_tf[c][k] + bias[o]
// M=8192 K=512 N=768. Zero LDS; both operands are ready frags in global.
__global__ __launch_bounds__(256) void phase2(const u16* __restrict__ nxtf,
                                              const u16* __restrict__ wtf,
                                              const float* __restrict__ bias,
                                              float* __restrict__ out) {
  const int t = threadIdx.x, l = t & 63, w = t >> 6;
  const int l15 = l & 15, l16 = l >> 4;
  const int m0 = blockIdx.x * 128, c0 = blockIdx.y * 48;
  f32x4 acc[2][3] = {};
  const u16* abase = nxtf + (size_t)l16 * 65536 + (size_t)(m0 + w * 32 + l15) * 8;
  const u16* bbase = wtf  + (size_t)l16 * 6144  + (size_t)(c0 + l15) * 8;
  float bv[3];
#pragma unroll
  for (int nt = 0; nt < 3; ++nt) bv[nt] = bias[(c0 + nt * 16 + l15) & 255];
#pragma unroll 2
  for (int step = 0; step < 16; ++step) {        // K: 32 per step
    u32x4 a[2], b[3];
    a[0] = *(const u32x4*)(abase + (size_t)step * 262144);
    a[1] = *(const u32x4*)(abase + (size_t)step * 262144 + 128);
#pragma unroll
    for (int nt = 0; nt < 3; ++nt)
      b[nt] = *(const u32x4*)(bbase + (size_t)step * 24576 + nt * 128);
#pragma unroll
    for (int mt2 = 0; mt2 < 2; ++mt2)
#pragma unroll
      for (int nt = 0; nt < 3; ++nt)
        acc[mt2][nt] = mfma16(a[mt2], b[nt], acc[mt2][nt]);
  }
  asm volatile("s_nop 7\n\ts_nop 7\n\ts_nop 7");
#pragma unroll
  for (int mt2 = 0; mt2 < 2; ++mt2)
#pragma unroll
    for (int nt = 0; nt < 3; ++nt) {
      int c = c0 + nt * 16 + l15;
      int kk = c >> 8, o = c & 255;
      float* op = out + (size_t)kk * 2097152 +
                  (size_t)(m0 + w * 32 + mt2 * 16 + l16 * 4) * 256 + o;
#pragma unroll
      for (int i = 0; i < 4; ++i)
        __builtin_nontemporal_store(acc[mt2][nt][i] + bv[nt], op + (size_t)i * 256);
    }
}

extern "C" void kernel_launch(void* const* d_in, const int* in_sizes, int n_in,
                              void* d_out, int out_size, void* d_ws, size_t ws_size,
                              hipStream_t stream) {
  (void)in_sizes; (void)n_in; (void)out_size; (void)ws_size;
  const float* x    = (const float*)d_in[1];
  const int*   adj  = (const int*)d_in[2];
  const float* wgt  = (const float*)d_in[3];
  const float* bias = (const float*)d_in[4];
  float* out = (float*)d_out;

  char* ws = (char*)d_ws;
  u16*   xtf  = (u16*)ws;                       // 4 MB
  u16*   nxtf = (u16*)(ws + (4ull  << 20));     // 8 MB
  u16*   wtf  = (u16*)(ws + (12ull << 20));     // 768 KB (pad to 1 MB)
  float* part = (float*)(ws + (13ull << 20));   // 64 MB (8 x 8192 x 256 f32)
  int*   degp = (int*)(ws + (77ull << 20));     // 256 KB

  prep   <<<2240, 256, 0, stream>>>(x, wgt, xtf, nxtf, wtf);
  phase1 <<<dim3(64, 8), 256, 0, stream>>>(adj, xtf, part, degp);
  reducek<<<1024, 256, 0, stream>>>(part, degp, nxtf);
  phase2 <<<dim3(64, 16), 256, 0, stream>>>(nxtf, wtf, bias, out);
}